// Round 1
// baseline (1057.259 us; speedup 1.0000x reference)
//
#include <hip/hip_runtime.h>
#include <hip/hip_bf16.h>
#include <math.h>

// ---------------- GEMM: out[m][j] = sum_k X[m][k]*W[j][k] + b[j] ----------------
// X: M x K row-major, W: Nout x K row-major (we multiply by W^T), out: M x Nout
__global__ __launch_bounds__(256) void gemm_xt(
    const float* __restrict__ X, const float* __restrict__ W,
    const float* __restrict__ b, float* __restrict__ out,
    int M, int K, int Nout) {
  const int BM = 64, BN = 64, BK = 16;
  __shared__ float As[BK][BM + 4];
  __shared__ float Bs[BK][BN + 4];
  int tid = threadIdx.x;          // 256 threads
  int tx = tid & 15, ty = tid >> 4;
  int m0 = blockIdx.y * BM, j0 = blockIdx.x * BN;
  float acc[4][4] = {};
  int ar = tid >> 2, ak = (tid & 3) * 4;
  for (int k0 = 0; k0 < K; k0 += BK) {
#pragma unroll
    for (int q = 0; q < 4; q++) {
      int gk = k0 + ak + q;
      int gm = m0 + ar;
      As[ak + q][ar] = (gm < M && gk < K) ? X[(long)gm * K + gk] : 0.f;
      int gj = j0 + ar;
      Bs[ak + q][ar] = (gj < Nout && gk < K) ? W[(long)gj * K + gk] : 0.f;
    }
    __syncthreads();
#pragma unroll
    for (int kk = 0; kk < BK; kk++) {
      float a[4], bb[4];
#pragma unroll
      for (int i = 0; i < 4; i++) a[i] = As[kk][ty * 4 + i];
#pragma unroll
      for (int j = 0; j < 4; j++) bb[j] = Bs[kk][tx * 4 + j];
#pragma unroll
      for (int i = 0; i < 4; i++)
#pragma unroll
        for (int j = 0; j < 4; j++) acc[i][j] += a[i] * bb[j];
    }
    __syncthreads();
  }
#pragma unroll
  for (int i = 0; i < 4; i++) {
    int gm = m0 + ty * 4 + i;
    if (gm >= M) continue;
#pragma unroll
    for (int j = 0; j < 4; j++) {
      int gj = j0 + tx * 4 + j;
      if (gj < Nout) out[(long)gm * Nout + gj] = acc[i][j] + b[gj];
    }
  }
}

// ---------------- CSR construction ----------------
__global__ void k_hist(const int* __restrict__ ei, int E, int N, int* __restrict__ deg) {
  int e = blockIdx.x * blockDim.x + threadIdx.x;
  int ET = E + N;
  if (e >= ET) return;
  int d = (e < E) ? ei[E + e] : (e - E);
  atomicAdd(&deg[d], 1);
}

__global__ void k_scan1(const int* __restrict__ deg, int N, int* __restrict__ rp,
                        int* __restrict__ bsum) {
  __shared__ int s[256];
  int b = blockIdx.x, t = threadIdx.x;
  int i = b * 256 + t;
  int v = (i < N) ? deg[i] : 0;
  s[t] = v;
  __syncthreads();
  for (int off = 1; off < 256; off <<= 1) {
    int x = (t >= off) ? s[t - off] : 0;
    __syncthreads();
    s[t] += x;
    __syncthreads();
  }
  if (i < N) rp[i + 1] = s[t];
  if (t == 255) bsum[b] = s[255];
}

__global__ void k_scan2(int* bsum, int nb) {
  if (threadIdx.x == 0 && blockIdx.x == 0) {
    int acc = 0;
    for (int i = 0; i < nb; i++) { int v = bsum[i]; bsum[i] = acc; acc += v; }
  }
}

__global__ void k_scan3(int* __restrict__ rp, const int* __restrict__ bsum, int N) {
  int i = blockIdx.x * blockDim.x + threadIdx.x;
  if (i == 0) rp[0] = 0;
  if (i < N) rp[i + 1] += bsum[i >> 8];
}

__global__ void k_copy_i32(const int* __restrict__ a, int* __restrict__ b, int n) {
  int i = blockIdx.x * blockDim.x + threadIdx.x;
  if (i < n) b[i] = a[i];
}

__global__ void k_scatter(const int* __restrict__ ei, int E, int N,
                          int* __restrict__ cursor, int* __restrict__ eids) {
  int e = blockIdx.x * blockDim.x + threadIdx.x;
  int ET = E + N;
  if (e >= ET) return;
  int d = (e < E) ? ei[E + e] : (e - E);
  int pos = atomicAdd(&cursor[d], 1);
  eids[pos] = e;
}

// ---------------- edge logits: one wave per edge ----------------
template <int HC, int Hn>
__global__ __launch_bounds__(256) void k_logits(
    const float* __restrict__ xl, const float* __restrict__ xr,
    const int* __restrict__ ei, int E, int N,
    const float* __restrict__ att, float* __restrict__ logits) {
  int wave = (blockIdx.x * blockDim.x + threadIdx.x) >> 6;
  int lane = threadIdx.x & 63;
  int ET = E + N;
  if (wave >= ET) return;
  int e = wave;
  int s = (e < E) ? ei[e] : (e - E);
  int d = (e < E) ? ei[E + e] : (e - E);
  const int CPL = HC / 64;  // channels per lane
  const float* pl = xl + (long)s * HC + lane * CPL;
  const float* pr = xr + (long)d * HC + lane * CPL;
  const float* pa = att + lane * CPL;
  float sum = 0.f;
#pragma unroll
  for (int c = 0; c < CPL; c++) {
    float v = pl[c] + pr[c];
    v = v > 0.f ? v : 0.2f * v;
    sum += v * pa[c];
  }
  const int G = 64 / Hn;  // lanes per head
#pragma unroll
  for (int off = G / 2; off >= 1; off >>= 1) sum += __shfl_xor(sum, off, 64);
  if ((lane & (G - 1)) == 0) {
    int h = lane / G;
    logits[(long)e * Hn + h] = sum;
  }
}

// ---------------- per-node softmax stats: one wave per node ----------------
template <int Hn>
__global__ __launch_bounds__(64) void k_softmax_stats(
    const float* __restrict__ logits, const int* __restrict__ rp,
    const int* __restrict__ eids, int N,
    float* __restrict__ mbuf, float* __restrict__ dbuf) {
  int n = blockIdx.x;
  int lane = threadIdx.x;
  int s0 = rp[n], s1 = rp[n + 1];
#pragma unroll
  for (int h = 0; h < Hn; h++) {
    float m = -INFINITY;
    for (int i = s0 + lane; i < s1; i += 64)
      m = fmaxf(m, logits[(long)eids[i] * Hn + h]);
#pragma unroll
    for (int off = 32; off >= 1; off >>= 1) m = fmaxf(m, __shfl_xor(m, off, 64));
    float sum = 0.f;
    for (int i = s0 + lane; i < s1; i += 64)
      sum += expf(logits[(long)eids[i] * Hn + h] - m);
#pragma unroll
    for (int off = 32; off >= 1; off >>= 1) sum += __shfl_xor(sum, off, 64);
    if (lane == 0) { mbuf[n * Hn + h] = m; dbuf[n * Hn + h] = sum; }
  }
}

// ---------------- aggregation: one block per node, thread = channel ----------------
template <int HC, int Hn, bool ELU>
__global__ __launch_bounds__(HC) void k_aggregate(
    const float* __restrict__ xl, const float* __restrict__ logits,
    const int* __restrict__ rp, const int* __restrict__ eids,
    const int* __restrict__ ei, int E, int N,
    const float* __restrict__ mbuf, const float* __restrict__ dbuf,
    const float* __restrict__ bias, float* __restrict__ out) {
  int n = blockIdx.x;
  int t = threadIdx.x;  // channel
  const int Cc = HC / Hn;
  int h = t / Cc;
  float m = mbuf[n * Hn + h];
  float inv = 1.f / (dbuf[n * Hn + h] + 1e-16f);
  int s0 = rp[n], s1 = rp[n + 1];
  float acc = 0.f;
  for (int i = s0; i < s1; i++) {
    int e = eids[i];
    int src = (e < E) ? ei[e] : (e - E);
    float alpha = expf(logits[(long)e * Hn + h] - m) * inv;
    acc += alpha * xl[(long)src * HC + t];
  }
  acc += bias[t];
  if (ELU) acc = acc > 0.f ? acc : expm1f(acc);
  out[(long)n * HC + t] = acc;
}

extern "C" void kernel_launch(void* const* d_in, const int* in_sizes, int n_in,
                              void* d_out, int out_size, void* d_ws, size_t ws_size,
                              hipStream_t stream) {
  const int IN = 77, Hh = 4, Cc = 128, HC = Hh * Cc;  // 512
  const int N = in_sizes[0] / IN;
  const int E = in_sizes[1] / 2;
  const int ET = E + N;

  const float* x   = (const float*)d_in[0];
  const int*   ei  = (const int*)d_in[1];
  const float* Wl1 = (const float*)d_in[2];  const float* bl1 = (const float*)d_in[3];
  const float* Wr1 = (const float*)d_in[4];  const float* br1 = (const float*)d_in[5];
  const float* att1= (const float*)d_in[6];  const float* b1  = (const float*)d_in[7];
  const float* Wl2 = (const float*)d_in[8];  const float* bl2 = (const float*)d_in[9];
  const float* Wr2 = (const float*)d_in[10]; const float* br2 = (const float*)d_in[11];
  const float* att2= (const float*)d_in[12]; const float* b2  = (const float*)d_in[13];
  const float* Wl3 = (const float*)d_in[14]; const float* bl3 = (const float*)d_in[15];
  const float* Wr3 = (const float*)d_in[16]; const float* br3 = (const float*)d_in[17];
  const float* att3= (const float*)d_in[18]; const float* b3  = (const float*)d_in[19];
  float* out = (float*)d_out;

  // workspace carve-up
  char* w = (char*)d_ws;
  size_t off = 0;
  auto alloc = [&](size_t bytes) -> void* {
    void* p = w + off;
    off += (bytes + 255) & ~(size_t)255;
    return p;
  };
  float* bufA   = (float*)alloc((size_t)N * HC * 4);
  float* xl     = (float*)alloc((size_t)N * HC * 4);
  float* xr     = (float*)alloc((size_t)N * HC * 4);
  float* logits = (float*)alloc((size_t)ET * Hh * 4);
  float* mbuf   = (float*)alloc((size_t)N * Hh * 4);
  float* dbuf   = (float*)alloc((size_t)N * Hh * 4);
  int*   deg    = (int*)alloc((size_t)N * 4);
  int*   rp     = (int*)alloc((size_t)(N + 1) * 4);
  int*   cursor = (int*)alloc((size_t)N * 4);
  int*   eids   = (int*)alloc((size_t)ET * 4);
  int*   bsum   = (int*)alloc(256 * 4);

  // ---- CSR build (by dst) ----
  hipMemsetAsync(deg, 0, (size_t)N * 4, stream);
  int tb = 256;
  k_hist<<<(ET + tb - 1) / tb, tb, 0, stream>>>(ei, E, N, deg);
  int nb = (N + 255) / 256;
  k_scan1<<<nb, 256, 0, stream>>>(deg, N, rp, bsum);
  k_scan2<<<1, 64, 0, stream>>>(bsum, nb);
  k_scan3<<<(N + 255) / 256, 256, 0, stream>>>(rp, bsum, N);
  k_copy_i32<<<(N + 255) / 256, 256, 0, stream>>>(rp, cursor, N);
  k_scatter<<<(ET + tb - 1) / tb, tb, 0, stream>>>(ei, E, N, cursor, eids);

  dim3 gemmBlk(256);
  int logitsBlocks = (ET * 64 + 255) / 256;

  // ---- layer 1: x (N x 77) -> bufA (N x 512), ELU ----
  {
    dim3 g((HC + 63) / 64, (N + 63) / 64);
    gemm_xt<<<g, gemmBlk, 0, stream>>>(x, Wl1, bl1, xl, N, IN, HC);
    gemm_xt<<<g, gemmBlk, 0, stream>>>(x, Wr1, br1, xr, N, IN, HC);
    k_logits<512, 4><<<logitsBlocks, 256, 0, stream>>>(xl, xr, ei, E, N, att1, logits);
    k_softmax_stats<4><<<N, 64, 0, stream>>>(logits, rp, eids, N, mbuf, dbuf);
    k_aggregate<512, 4, true><<<N, 512, 0, stream>>>(xl, logits, rp, eids, ei, E, N,
                                                     mbuf, dbuf, b1, bufA);
  }
  // ---- layer 2: bufA -> bufA, ELU ----
  {
    dim3 g((HC + 63) / 64, (N + 63) / 64);
    gemm_xt<<<g, gemmBlk, 0, stream>>>(bufA, Wl2, bl2, xl, N, HC, HC);
    gemm_xt<<<g, gemmBlk, 0, stream>>>(bufA, Wr2, br2, xr, N, HC, HC);
    k_logits<512, 4><<<logitsBlocks, 256, 0, stream>>>(xl, xr, ei, E, N, att2, logits);
    k_softmax_stats<4><<<N, 64, 0, stream>>>(logits, rp, eids, N, mbuf, dbuf);
    k_aggregate<512, 4, true><<<N, 512, 0, stream>>>(xl, logits, rp, eids, ei, E, N,
                                                     mbuf, dbuf, b2, bufA);
  }
  // ---- layer 3: bufA -> out (N x 128), no ELU ----
  {
    dim3 g((Cc + 63) / 64, (N + 63) / 64);
    gemm_xt<<<g, gemmBlk, 0, stream>>>(bufA, Wl3, bl3, xl, N, HC, Cc);
    gemm_xt<<<g, gemmBlk, 0, stream>>>(bufA, Wr3, br3, xr, N, HC, Cc);
    k_logits<128, 1><<<logitsBlocks, 256, 0, stream>>>(xl, xr, ei, E, N, att3, logits);
    k_softmax_stats<1><<<N, 64, 0, stream>>>(logits, rp, eids, N, mbuf, dbuf);
    k_aggregate<128, 1, false><<<N, 128, 0, stream>>>(xl, logits, rp, eids, ei, E, N,
                                                      mbuf, dbuf, b3, out);
  }
}

// Round 2
// 614.520 us; speedup vs baseline: 1.7205x; 1.7205x over previous
//
#include <hip/hip_runtime.h>
#include <hip/hip_bf16.h>
#include <math.h>

typedef __attribute__((ext_vector_type(8))) short short8;
typedef __attribute__((ext_vector_type(4))) float f32x4;

__device__ __forceinline__ void load_lds16(const void* g, void* l) {
  __builtin_amdgcn_global_load_lds(
      (const __attribute__((address_space(1))) unsigned int*)g,
      (__attribute__((address_space(3))) unsigned int*)l, 16, 0, 0);
}

// ---------------- bf16 MFMA GEMM ----------------
// A: M x K bf16 row-major (K mult of 32). B: Nout x K bf16 row-major (= W, we do X@W^T).
// out: M x Nout fp32, bias = bl[col] for col<halfN else br[col-halfN].
__global__ __launch_bounds__(256) void gemm_mfma(
    const __hip_bfloat16* __restrict__ A, const __hip_bfloat16* __restrict__ B,
    const float* __restrict__ bl, const float* __restrict__ br, int halfN,
    float* __restrict__ out, int M, int K, int Nout) {
  __shared__ __hip_bfloat16 As[128 * 32];
  __shared__ __hip_bfloat16 Bs[128 * 32];
  int t = threadIdx.x;
  int w = t >> 6, l = t & 63;
  int lr = l & 15, lh = l >> 4;
  int wr = w >> 1, wc = w & 1;  // wave's 64x64 quadrant
  int m0 = blockIdx.y * 128, n0 = blockIdx.x * 128;
  f32x4 acc[4][4] = {};
  int nk = K >> 5;
  for (int ks = 0; ks < nk; ++ks) {
    int k0 = ks << 5;
#pragma unroll
    for (int p = 0; p < 2; ++p) {
      int c = p * 256 + t;           // 16B-chunk id within 8KB tile
      int row = c >> 2, sub = c & 3;
      int gm = m0 + row; if (gm >= M) gm = M - 1;
      const __hip_bfloat16* gsrc = A + (size_t)gm * K + k0 + sub * 8;
      char* ldst = (char*)As + (size_t)(p * 256 + w * 64) * 16;
      load_lds16(gsrc, ldst);
    }
#pragma unroll
    for (int p = 0; p < 2; ++p) {
      int c = p * 256 + t;
      int row = c >> 2, sub = c & 3;
      const __hip_bfloat16* gsrc = B + (size_t)(n0 + row) * K + k0 + sub * 8;
      char* ldst = (char*)Bs + (size_t)(p * 256 + w * 64) * 16;
      load_lds16(gsrc, ldst);
    }
    __syncthreads();
    short8 af[4], bf[4];
#pragma unroll
    for (int mt = 0; mt < 4; ++mt)
      af[mt] = *(const short8*)(As + (size_t)(wr * 64 + mt * 16 + lr) * 32 + lh * 8);
#pragma unroll
    for (int nt = 0; nt < 4; ++nt)
      bf[nt] = *(const short8*)(Bs + (size_t)(wc * 64 + nt * 16 + lr) * 32 + lh * 8);
#pragma unroll
    for (int mt = 0; mt < 4; ++mt)
#pragma unroll
      for (int nt = 0; nt < 4; ++nt)
        acc[mt][nt] = __builtin_amdgcn_mfma_f32_16x16x32_bf16(af[mt], bf[nt], acc[mt][nt], 0, 0, 0);
    __syncthreads();
  }
  // epilogue: C/D layout col=lane&15, row=(lane>>4)*4+reg   [m89/m91]
#pragma unroll
  for (int mt = 0; mt < 4; ++mt) {
#pragma unroll
    for (int r = 0; r < 4; ++r) {
      int gm = m0 + wr * 64 + mt * 16 + lh * 4 + r;
      if (gm >= M) continue;
#pragma unroll
      for (int nt = 0; nt < 4; ++nt) {
        int gn = n0 + wc * 64 + nt * 16 + lr;
        float bv = (gn < halfN) ? bl[gn] : br[gn - halfN];
        out[(size_t)gm * Nout + gn] = acc[mt][nt][r] + bv;
      }
    }
  }
}

// ---------------- casts ----------------
__global__ void k_cast_pad(const float* __restrict__ src, __hip_bfloat16* __restrict__ dst,
                           int rows, int K, int Kp, int row0) {
  int i = blockIdx.x * blockDim.x + threadIdx.x;
  int total = rows * Kp;
  if (i >= total) return;
  int r = i / Kp, k = i - r * Kp;
  float v = (k < K) ? src[(size_t)r * K + k] : 0.f;
  dst[(size_t)(row0 + r) * Kp + k] = __float2bfloat16(v);
}

// ---------------- CSR construction ----------------
__global__ void k_hist(const int* __restrict__ ei, int E, int N, int* __restrict__ deg) {
  int e = blockIdx.x * blockDim.x + threadIdx.x;
  int ET = E + N;
  if (e >= ET) return;
  int d = (e < E) ? ei[E + e] : (e - E);
  atomicAdd(&deg[d], 1);
}

__global__ void k_scan1(const int* __restrict__ deg, int N, int* __restrict__ rp,
                        int* __restrict__ bsum) {
  __shared__ int s[256];
  int b = blockIdx.x, t = threadIdx.x;
  int i = b * 256 + t;
  int v = (i < N) ? deg[i] : 0;
  s[t] = v;
  __syncthreads();
  for (int off = 1; off < 256; off <<= 1) {
    int x = (t >= off) ? s[t - off] : 0;
    __syncthreads();
    s[t] += x;
    __syncthreads();
  }
  if (i < N) rp[i + 1] = s[t];
  if (t == 255) bsum[b] = s[255];
}

__global__ void k_scan2(int* bsum, int nb) {
  if (threadIdx.x == 0 && blockIdx.x == 0) {
    int acc = 0;
    for (int i = 0; i < nb; i++) { int v = bsum[i]; bsum[i] = acc; acc += v; }
  }
}

__global__ void k_scan3(int* __restrict__ rp, const int* __restrict__ bsum, int N) {
  int i = blockIdx.x * blockDim.x + threadIdx.x;
  if (i == 0) rp[0] = 0;
  if (i < N) rp[i + 1] += bsum[i >> 8];
}

__global__ void k_copy_i32(const int* __restrict__ a, int* __restrict__ b, int n) {
  int i = blockIdx.x * blockDim.x + threadIdx.x;
  if (i < n) b[i] = a[i];
}

__global__ void k_scatter(const int* __restrict__ ei, int E, int N,
                          int* __restrict__ cursor, int* __restrict__ eids) {
  int e = blockIdx.x * blockDim.x + threadIdx.x;
  int ET = E + N;
  if (e >= ET) return;
  int d = (e < E) ? ei[E + e] : (e - E);
  int pos = atomicAdd(&cursor[d], 1);
  eids[pos] = e;
}

// ---------------- edge logits: one wave per edge ----------------
template <int HC, int Hn>
__global__ __launch_bounds__(256) void k_logits(
    const float* __restrict__ xl, const float* __restrict__ xr, int LD,
    const int* __restrict__ ei, int E, int N,
    const float* __restrict__ att, float* __restrict__ logits) {
  int wave = (blockIdx.x * blockDim.x + threadIdx.x) >> 6;
  int lane = threadIdx.x & 63;
  int ET = E + N;
  if (wave >= ET) return;
  int e = wave;
  int s = (e < E) ? ei[e] : (e - E);
  int d = (e < E) ? ei[E + e] : (e - E);
  const int CPL = HC / 64;
  const float* pl = xl + (size_t)s * LD + lane * CPL;
  const float* pr = xr + (size_t)d * LD + lane * CPL;
  const float* pa = att + lane * CPL;
  float sum = 0.f;
#pragma unroll
  for (int c = 0; c < CPL; c++) {
    float v = pl[c] + pr[c];
    v = v > 0.f ? v : 0.2f * v;
    sum += v * pa[c];
  }
  const int G = 64 / Hn;
#pragma unroll
  for (int off = G / 2; off >= 1; off >>= 1) sum += __shfl_xor(sum, off, 64);
  if ((lane & (G - 1)) == 0) {
    int h = lane / G;
    logits[(size_t)e * Hn + h] = sum;
  }
}

// ---------------- per-node softmax stats: one wave per node ----------------
template <int Hn>
__global__ __launch_bounds__(64) void k_softmax_stats(
    const float* __restrict__ logits, const int* __restrict__ rp,
    const int* __restrict__ eids, int N,
    float* __restrict__ mbuf, float* __restrict__ dbuf) {
  int n = blockIdx.x;
  int lane = threadIdx.x;
  int s0 = rp[n], s1 = rp[n + 1];
#pragma unroll
  for (int h = 0; h < Hn; h++) {
    float m = -INFINITY;
    for (int i = s0 + lane; i < s1; i += 64)
      m = fmaxf(m, logits[(size_t)eids[i] * Hn + h]);
#pragma unroll
    for (int off = 32; off >= 1; off >>= 1) m = fmaxf(m, __shfl_xor(m, off, 64));
    float sum = 0.f;
    for (int i = s0 + lane; i < s1; i += 64)
      sum += expf(logits[(size_t)eids[i] * Hn + h] - m);
#pragma unroll
    for (int off = 32; off >= 1; off >>= 1) sum += __shfl_xor(sum, off, 64);
    if (lane == 0) { mbuf[n * Hn + h] = m; dbuf[n * Hn + h] = sum; }
  }
}

// ---------------- aggregation: one block per node, thread = channel ----------------
template <int HC, int Hn, bool ELU, typename OutT>
__global__ __launch_bounds__(HC) void k_aggregate(
    const float* __restrict__ xl, int LD, const float* __restrict__ logits,
    const int* __restrict__ rp, const int* __restrict__ eids,
    const int* __restrict__ ei, int E, int N,
    const float* __restrict__ mbuf, const float* __restrict__ dbuf,
    const float* __restrict__ bias, OutT* __restrict__ out) {
  int n = blockIdx.x;
  int t = threadIdx.x;
  const int Cc = HC / Hn;
  int h = t / Cc;
  float m = mbuf[n * Hn + h];
  float inv = 1.f / (dbuf[n * Hn + h] + 1e-16f);
  int s0 = rp[n], s1 = rp[n + 1];
  float acc = 0.f;
  for (int i = s0; i < s1; i++) {
    int e = eids[i];
    int src = (e < E) ? ei[e] : (e - E);
    float alpha = expf(logits[(size_t)e * Hn + h] - m) * inv;
    acc += alpha * xl[(size_t)src * LD + t];
  }
  acc += bias[t];
  if (ELU) acc = acc > 0.f ? acc : expm1f(acc);
  if constexpr (sizeof(OutT) == 2)
    out[(size_t)n * HC + t] = __float2bfloat16(acc);
  else
    out[(size_t)n * HC + t] = acc;
}

extern "C" void kernel_launch(void* const* d_in, const int* in_sizes, int n_in,
                              void* d_out, int out_size, void* d_ws, size_t ws_size,
                              hipStream_t stream) {
  const int IN = 77, Kp1 = 96, Hh = 4, Cc = 128, HC = Hh * Cc;  // 512
  const int N = in_sizes[0] / IN;
  const int E = in_sizes[1] / 2;
  const int ET = E + N;

  const float* x   = (const float*)d_in[0];
  const int*   ei  = (const int*)d_in[1];
  const float* Wl1 = (const float*)d_in[2];  const float* bl1 = (const float*)d_in[3];
  const float* Wr1 = (const float*)d_in[4];  const float* br1 = (const float*)d_in[5];
  const float* att1= (const float*)d_in[6];  const float* b1  = (const float*)d_in[7];
  const float* Wl2 = (const float*)d_in[8];  const float* bl2 = (const float*)d_in[9];
  const float* Wr2 = (const float*)d_in[10]; const float* br2 = (const float*)d_in[11];
  const float* att2= (const float*)d_in[12]; const float* b2  = (const float*)d_in[13];
  const float* Wl3 = (const float*)d_in[14]; const float* bl3 = (const float*)d_in[15];
  const float* Wr3 = (const float*)d_in[16]; const float* br3 = (const float*)d_in[17];
  const float* att3= (const float*)d_in[18]; const float* b3  = (const float*)d_in[19];
  float* out = (float*)d_out;

  // workspace carve-up
  char* w = (char*)d_ws;
  size_t off = 0;
  auto alloc = [&](size_t bytes) -> void* {
    void* p = w + off;
    off += (bytes + 255) & ~(size_t)255;
    return p;
  };
  float* xlr  = (float*)alloc((size_t)N * 2 * HC * 4);           // 40 MB, GEMM out
  __hip_bfloat16* hb  = (__hip_bfloat16*)alloc((size_t)N * HC * 2);  // 10 MB, bf16 activations
  __hip_bfloat16* Wc1 = (__hip_bfloat16*)alloc((size_t)2 * HC * Kp1 * 2);
  __hip_bfloat16* Wc2 = (__hip_bfloat16*)alloc((size_t)2 * HC * HC * 2);
  __hip_bfloat16* Wc3 = (__hip_bfloat16*)alloc((size_t)2 * Cc * HC * 2);
  float* logits = (float*)alloc((size_t)ET * Hh * 4);
  float* mbuf   = (float*)alloc((size_t)N * Hh * 4);
  float* dbuf   = (float*)alloc((size_t)N * Hh * 4);
  int*   deg    = (int*)alloc((size_t)N * 4);
  int*   rp     = (int*)alloc((size_t)(N + 1) * 4);
  int*   cursor = (int*)alloc((size_t)N * 4);
  int*   eids   = (int*)alloc((size_t)ET * 4);
  int*   bsum   = (int*)alloc(256 * 4);

  // ---- weight + input casts (bf16) ----
  auto cast_launch = [&](const float* src, __hip_bfloat16* dst, int rows, int K, int Kpad, int row0) {
    int total = rows * Kpad;
    k_cast_pad<<<(total + 255) / 256, 256, 0, stream>>>(src, dst, rows, K, Kpad, row0);
  };
  cast_launch(Wl1, Wc1, HC, IN, Kp1, 0);
  cast_launch(Wr1, Wc1, HC, IN, Kp1, HC);
  cast_launch(Wl2, Wc2, HC, HC, HC, 0);
  cast_launch(Wr2, Wc2, HC, HC, HC, HC);
  cast_launch(Wl3, Wc3, Cc, HC, HC, 0);
  cast_launch(Wr3, Wc3, Cc, HC, HC, Cc);
  cast_launch(x, hb, N, IN, Kp1, 0);  // x -> bf16 padded to 96, aliased into hb

  // ---- CSR build (by dst) ----
  hipMemsetAsync(deg, 0, (size_t)N * 4, stream);
  int tb = 256;
  k_hist<<<(ET + tb - 1) / tb, tb, 0, stream>>>(ei, E, N, deg);
  int nb = (N + 255) / 256;
  k_scan1<<<nb, 256, 0, stream>>>(deg, N, rp, bsum);
  k_scan2<<<1, 64, 0, stream>>>(bsum, nb);
  k_scan3<<<(N + 255) / 256, 256, 0, stream>>>(rp, bsum, N);
  k_copy_i32<<<(N + 255) / 256, 256, 0, stream>>>(rp, cursor, N);
  k_scatter<<<(ET + tb - 1) / tb, tb, 0, stream>>>(ei, E, N, cursor, eids);

  int logitsBlocks = (ET * 64 + 255) / 256;
  int mb = (N + 127) / 128;

  // ---- layer 1: hb(as N x 96) -> xlr (N x 1024) -> hb (N x 512 bf16) ----
  {
    dim3 g(2 * HC / 128, mb);
    gemm_mfma<<<g, 256, 0, stream>>>(hb, Wc1, bl1, br1, HC, xlr, N, Kp1, 2 * HC);
    k_logits<512, 4><<<logitsBlocks, 256, 0, stream>>>(xlr, xlr + HC, 2 * HC, ei, E, N, att1, logits);
    k_softmax_stats<4><<<N, 64, 0, stream>>>(logits, rp, eids, N, mbuf, dbuf);
    k_aggregate<512, 4, true, __hip_bfloat16><<<N, 512, 0, stream>>>(
        xlr, 2 * HC, logits, rp, eids, ei, E, N, mbuf, dbuf, b1, hb);
  }
  // ---- layer 2: hb -> xlr -> hb ----
  {
    dim3 g(2 * HC / 128, mb);
    gemm_mfma<<<g, 256, 0, stream>>>(hb, Wc2, bl2, br2, HC, xlr, N, HC, 2 * HC);
    k_logits<512, 4><<<logitsBlocks, 256, 0, stream>>>(xlr, xlr + HC, 2 * HC, ei, E, N, att2, logits);
    k_softmax_stats<4><<<N, 64, 0, stream>>>(logits, rp, eids, N, mbuf, dbuf);
    k_aggregate<512, 4, true, __hip_bfloat16><<<N, 512, 0, stream>>>(
        xlr, 2 * HC, logits, rp, eids, ei, E, N, mbuf, dbuf, b2, hb);
  }
  // ---- layer 3: hb -> xlr (N x 256) -> out (N x 128 fp32) ----
  {
    dim3 g(2 * Cc / 128, mb);
    gemm_mfma<<<g, 256, 0, stream>>>(hb, Wc3, bl3, br3, Cc, xlr, N, HC, 2 * Cc);
    k_logits<128, 1><<<logitsBlocks, 256, 0, stream>>>(xlr, xlr + Cc, 2 * Cc, ei, E, N, att3, logits);
    k_softmax_stats<1><<<N, 64, 0, stream>>>(logits, rp, eids, N, mbuf, dbuf);
    k_aggregate<128, 1, false, float><<<N, 128, 0, stream>>>(
        xlr, 2 * Cc, logits, rp, eids, ei, E, N, mbuf, dbuf, b3, out);
  }
}

// Round 3
// 307.648 us; speedup vs baseline: 3.4366x; 1.9975x over previous
//
#include <hip/hip_runtime.h>
#include <hip/hip_bf16.h>
#include <math.h>

typedef __attribute__((ext_vector_type(8))) short short8;
typedef __attribute__((ext_vector_type(4))) float f32x4;
typedef __attribute__((ext_vector_type(2))) float f32x2;

__device__ __forceinline__ float bf2f(unsigned short u) {
  union { unsigned int i; float f; } x; x.i = ((unsigned int)u) << 16; return x.f;
}

__device__ __forceinline__ void load_lds16(const void* g, void* l) {
  __builtin_amdgcn_global_load_lds(
      (const __attribute__((address_space(1))) unsigned int*)g,
      (__attribute__((address_space(3))) unsigned int*)l, 16, 0, 0);
}

// ---------------- bf16 MFMA GEMM, bf16 output ----------------
// A: M x K bf16 row-major (K mult of 32). B: Nout x K bf16 (= concat W, X@W^T).
// out: M x Nout bf16, bias = bl[col] for col<halfN else br[col-halfN].
__global__ __launch_bounds__(256) void gemm_mfma(
    const __hip_bfloat16* __restrict__ A, const __hip_bfloat16* __restrict__ B,
    const float* __restrict__ bl, const float* __restrict__ br, int halfN,
    __hip_bfloat16* __restrict__ out, int M, int K, int Nout) {
  __shared__ __hip_bfloat16 As[128 * 32];
  __shared__ __hip_bfloat16 Bs[128 * 32];
  int t = threadIdx.x;
  int w = t >> 6, l = t & 63;
  int lr = l & 15, lh = l >> 4;
  int wr = w >> 1, wc = w & 1;
  int m0 = blockIdx.y * 128, n0 = blockIdx.x * 128;
  f32x4 acc[4][4] = {};
  int nk = K >> 5;
  for (int ks = 0; ks < nk; ++ks) {
    int k0 = ks << 5;
#pragma unroll
    for (int p = 0; p < 2; ++p) {
      int c = p * 256 + t;
      int row = c >> 2, sub = c & 3;
      int gm = m0 + row; if (gm >= M) gm = M - 1;
      const __hip_bfloat16* gsrc = A + (size_t)gm * K + k0 + sub * 8;
      char* ldst = (char*)As + (size_t)(p * 256 + w * 64) * 16;
      load_lds16(gsrc, ldst);
    }
#pragma unroll
    for (int p = 0; p < 2; ++p) {
      int c = p * 256 + t;
      int row = c >> 2, sub = c & 3;
      const __hip_bfloat16* gsrc = B + (size_t)(n0 + row) * K + k0 + sub * 8;
      char* ldst = (char*)Bs + (size_t)(p * 256 + w * 64) * 16;
      load_lds16(gsrc, ldst);
    }
    __syncthreads();
    short8 af[4], bf[4];
#pragma unroll
    for (int mt = 0; mt < 4; ++mt)
      af[mt] = *(const short8*)(As + (size_t)(wr * 64 + mt * 16 + lr) * 32 + lh * 8);
#pragma unroll
    for (int nt = 0; nt < 4; ++nt)
      bf[nt] = *(const short8*)(Bs + (size_t)(wc * 64 + nt * 16 + lr) * 32 + lh * 8);
#pragma unroll
    for (int mt = 0; mt < 4; ++mt)
#pragma unroll
      for (int nt = 0; nt < 4; ++nt)
        acc[mt][nt] = __builtin_amdgcn_mfma_f32_16x16x32_bf16(af[mt], bf[nt], acc[mt][nt], 0, 0, 0);
    __syncthreads();
  }
  // C/D layout: col=lane&15, row=(lane>>4)*4+reg
#pragma unroll
  for (int mt = 0; mt < 4; ++mt) {
#pragma unroll
    for (int r = 0; r < 4; ++r) {
      int gm = m0 + wr * 64 + mt * 16 + lh * 4 + r;
      if (gm >= M) continue;
#pragma unroll
      for (int nt = 0; nt < 4; ++nt) {
        int gn = n0 + wc * 64 + nt * 16 + lr;
        float bv = (gn < halfN) ? bl[gn] : br[gn - halfN];
        out[(size_t)gm * Nout + gn] = __float2bfloat16(acc[mt][nt][r] + bv);
      }
    }
  }
}

// ---------------- casts ----------------
__global__ void k_cast_pad(const float* __restrict__ src, __hip_bfloat16* __restrict__ dst,
                           int rows, int K, int Kp, int row0) {
  int i = blockIdx.x * blockDim.x + threadIdx.x;
  int total = rows * Kp;
  if (i >= total) return;
  int r = i / Kp, k = i - r * Kp;
  float v = (k < K) ? src[(size_t)r * K + k] : 0.f;
  dst[(size_t)(row0 + r) * Kp + k] = __float2bfloat16(v);
}

// ---------------- CSR construction ----------------
__global__ void k_hist(const int* __restrict__ ei, int E, int N, int* __restrict__ deg) {
  int e = blockIdx.x * blockDim.x + threadIdx.x;
  int ET = E + N;
  if (e >= ET) return;
  int d = (e < E) ? ei[E + e] : (e - E);
  atomicAdd(&deg[d], 1);
}

__global__ void k_scan1(const int* __restrict__ deg, int N, int* __restrict__ rp,
                        int* __restrict__ bsum) {
  __shared__ int s[256];
  int b = blockIdx.x, t = threadIdx.x;
  int i = b * 256 + t;
  int v = (i < N) ? deg[i] : 0;
  s[t] = v;
  __syncthreads();
  for (int off = 1; off < 256; off <<= 1) {
    int x = (t >= off) ? s[t - off] : 0;
    __syncthreads();
    s[t] += x;
    __syncthreads();
  }
  if (i < N) rp[i + 1] = s[t];
  if (t == 255) bsum[b] = s[255];
}

__global__ void k_scan2(int* bsum, int nb) {
  if (threadIdx.x == 0 && blockIdx.x == 0) {
    int acc = 0;
    for (int i = 0; i < nb; i++) { int v = bsum[i]; bsum[i] = acc; acc += v; }
  }
}

__global__ void k_scan3(int* __restrict__ rp, const int* __restrict__ bsum, int N) {
  int i = blockIdx.x * blockDim.x + threadIdx.x;
  if (i == 0) rp[0] = 0;
  if (i < N) rp[i + 1] += bsum[i >> 8];
}

__global__ void k_copy_i32(const int* __restrict__ a, int* __restrict__ b, int n) {
  int i = blockIdx.x * blockDim.x + threadIdx.x;
  if (i < n) b[i] = a[i];
}

__global__ void k_scatter(const int* __restrict__ ei, int E, int N,
                          int* __restrict__ cursor,
                          int* __restrict__ srcs, int* __restrict__ dsts) {
  int e = blockIdx.x * blockDim.x + threadIdx.x;
  int ET = E + N;
  if (e >= ET) return;
  int s = (e < E) ? ei[e] : (e - E);
  int d = (e < E) ? ei[E + e] : (e - E);
  int pos = atomicAdd(&cursor[d], 1);
  srcs[pos] = s;
  dsts[pos] = d;
}

// ---------------- edge logits (CSR order): grid-stride, one wave per edge ----------------
template <int HC, int Hn>
__global__ __launch_bounds__(256) void k_logits(
    const __hip_bfloat16* __restrict__ xl, const __hip_bfloat16* __restrict__ xr, int LD,
    const int* __restrict__ srcs, const int* __restrict__ dsts, int ET,
    const float* __restrict__ att, float* __restrict__ ls) {
  const int CPL = HC / 64;
  int lane = threadIdx.x & 63;
  int wid = (blockIdx.x * blockDim.x + threadIdx.x) >> 6;
  int nw = (gridDim.x * blockDim.x) >> 6;
  float a[CPL];
#pragma unroll
  for (int c = 0; c < CPL; c++) a[c] = att[lane * CPL + c];
  for (int pos = wid; pos < ET; pos += nw) {
    int s = srcs[pos], d = dsts[pos];
    float sum = 0.f;
    if constexpr (CPL == 8) {
      short8 vl = *(const short8*)(xl + (size_t)s * LD + lane * 8);
      short8 vr = *(const short8*)(xr + (size_t)d * LD + lane * 8);
#pragma unroll
      for (int c = 0; c < 8; c++) {
        float v = bf2f((unsigned short)vl[c]) + bf2f((unsigned short)vr[c]);
        v = v > 0.f ? v : 0.2f * v;
        sum += v * a[c];
      }
    } else {
      unsigned int vl = *(const unsigned int*)(xl + (size_t)s * LD + lane * 2);
      unsigned int vr = *(const unsigned int*)(xr + (size_t)d * LD + lane * 2);
#pragma unroll
      for (int c = 0; c < 2; c++) {
        float v = bf2f((unsigned short)(c ? (vl >> 16) : (vl & 0xffff))) +
                  bf2f((unsigned short)(c ? (vr >> 16) : (vr & 0xffff)));
        v = v > 0.f ? v : 0.2f * v;
        sum += v * a[c];
      }
    }
    const int G = 64 / Hn;
#pragma unroll
    for (int off = G / 2; off >= 1; off >>= 1) sum += __shfl_xor(sum, off, 64);
    if ((lane & (G - 1)) == 0) ls[(size_t)pos * Hn + (lane / G)] = sum;
  }
}

// ---------------- per-node softmax stats + in-place alpha: one wave per node ----------------
template <int Hn>
__global__ __launch_bounds__(256) void k_stats_alpha(
    float* __restrict__ ls, const int* __restrict__ rp, int N) {
  int lane = threadIdx.x & 63;
  int n = (blockIdx.x * blockDim.x + threadIdx.x) >> 6;
  if (n >= N) return;
  int s0 = rp[n], s1 = rp[n + 1];
  const int EPW = 64 / Hn;                 // edge slots per pass
  const int LH = (Hn == 4) ? 2 : 0;
  int h = lane & (Hn - 1);
  int io = lane >> LH;
  float m = -INFINITY;
  for (int i = s0 + io; i < s1; i += EPW) m = fmaxf(m, ls[(size_t)i * Hn + h]);
#pragma unroll
  for (int off = Hn; off < 64; off <<= 1) m = fmaxf(m, __shfl_xor(m, off, 64));
  float sum = 0.f;
  for (int i = s0 + io; i < s1; i += EPW) sum += expf(ls[(size_t)i * Hn + h] - m);
#pragma unroll
  for (int off = Hn; off < 64; off <<= 1) sum += __shfl_xor(sum, off, 64);
  float inv = 1.f / (sum + 1e-16f);
  for (int i = s0 + io; i < s1; i += EPW) {
    size_t idx = (size_t)i * Hn + h;
    ls[idx] = expf(ls[idx] - m) * inv;
  }
}

// ---------------- aggregation: one wave per node, lane = 8 (or 2) channels ----------------
template <int HC, int Hn, bool ELU, typename OutT>
__global__ __launch_bounds__(256) void k_aggregate(
    const __hip_bfloat16* __restrict__ xl, int LD, const float* __restrict__ alpha,
    const int* __restrict__ rp, const int* __restrict__ srcs,
    const float* __restrict__ bias, int N, OutT* __restrict__ out) {
  const int CPL = HC / 64;
  int lane = threadIdx.x & 63;
  int n = (blockIdx.x * blockDim.x + threadIdx.x) >> 6;
  if (n >= N) return;
  const int Cc = HC / Hn;
  int h = (lane * CPL) / Cc;
  int s0 = rp[n], s1 = rp[n + 1];
  float acc[CPL] = {};
  for (int i = s0; i < s1; i++) {
    int s = srcs[i];
    float al = alpha[(size_t)i * Hn + h];
    if constexpr (CPL == 8) {
      short8 v = *(const short8*)(xl + (size_t)s * LD + lane * 8);
#pragma unroll
      for (int c = 0; c < 8; c++) acc[c] += al * bf2f((unsigned short)v[c]);
    } else {
      unsigned int v = *(const unsigned int*)(xl + (size_t)s * LD + lane * 2);
      acc[0] += al * bf2f((unsigned short)(v & 0xffff));
      acc[1] += al * bf2f((unsigned short)(v >> 16));
    }
  }
#pragma unroll
  for (int c = 0; c < CPL; c++) {
    float r = acc[c] + bias[lane * CPL + c];
    if (ELU) r = r > 0.f ? r : expm1f(r);
    acc[c] = r;
  }
  if constexpr (sizeof(OutT) == 2) {
    short8 o;
#pragma unroll
    for (int c = 0; c < CPL; c++) {
      __hip_bfloat16 bv = __float2bfloat16(acc[c]);
      o[c] = __builtin_bit_cast(short, bv);
    }
    *(short8*)((__hip_bfloat16*)out + (size_t)n * HC + lane * CPL) = o;
  } else {
    f32x2 o; o.x = acc[0]; o.y = acc[1];
    *(f32x2*)((float*)out + (size_t)n * HC + lane * 2) = o;
  }
}

extern "C" void kernel_launch(void* const* d_in, const int* in_sizes, int n_in,
                              void* d_out, int out_size, void* d_ws, size_t ws_size,
                              hipStream_t stream) {
  const int IN = 77, Kp1 = 96, Hh = 4, Cc = 128, HC = Hh * Cc;  // 512
  const int N = in_sizes[0] / IN;
  const int E = in_sizes[1] / 2;
  const int ET = E + N;

  const float* x   = (const float*)d_in[0];
  const int*   ei  = (const int*)d_in[1];
  const float* Wl1 = (const float*)d_in[2];  const float* bl1 = (const float*)d_in[3];
  const float* Wr1 = (const float*)d_in[4];  const float* br1 = (const float*)d_in[5];
  const float* att1= (const float*)d_in[6];  const float* b1  = (const float*)d_in[7];
  const float* Wl2 = (const float*)d_in[8];  const float* bl2 = (const float*)d_in[9];
  const float* Wr2 = (const float*)d_in[10]; const float* br2 = (const float*)d_in[11];
  const float* att2= (const float*)d_in[12]; const float* b2  = (const float*)d_in[13];
  const float* Wl3 = (const float*)d_in[14]; const float* bl3 = (const float*)d_in[15];
  const float* Wr3 = (const float*)d_in[16]; const float* br3 = (const float*)d_in[17];
  const float* att3= (const float*)d_in[18]; const float* b3  = (const float*)d_in[19];
  float* out = (float*)d_out;

  char* w = (char*)d_ws;
  size_t off = 0;
  auto alloc = [&](size_t bytes) -> void* {
    void* p = w + off;
    off += (bytes + 255) & ~(size_t)255;
    return p;
  };
  __hip_bfloat16* xlr = (__hip_bfloat16*)alloc((size_t)N * 2 * HC * 2);  // 20 MB
  __hip_bfloat16* hb  = (__hip_bfloat16*)alloc((size_t)N * HC * 2);      // 10 MB
  __hip_bfloat16* Wc1 = (__hip_bfloat16*)alloc((size_t)2 * HC * Kp1 * 2);
  __hip_bfloat16* Wc2 = (__hip_bfloat16*)alloc((size_t)2 * HC * HC * 2);
  __hip_bfloat16* Wc3 = (__hip_bfloat16*)alloc((size_t)2 * Cc * HC * 2);
  float* ls     = (float*)alloc((size_t)ET * Hh * 4);
  int*   deg    = (int*)alloc((size_t)N * 4);
  int*   rp     = (int*)alloc((size_t)(N + 1) * 4);
  int*   cursor = (int*)alloc((size_t)N * 4);
  int*   srcs   = (int*)alloc((size_t)ET * 4);
  int*   dsts   = (int*)alloc((size_t)ET * 4);
  int*   bsum   = (int*)alloc(256 * 4);

  auto cast_launch = [&](const float* src, __hip_bfloat16* dst, int rows, int K, int Kpad, int row0) {
    int total = rows * Kpad;
    k_cast_pad<<<(total + 255) / 256, 256, 0, stream>>>(src, dst, rows, K, Kpad, row0);
  };
  cast_launch(Wl1, Wc1, HC, IN, Kp1, 0);
  cast_launch(Wr1, Wc1, HC, IN, Kp1, HC);
  cast_launch(Wl2, Wc2, HC, HC, HC, 0);
  cast_launch(Wr2, Wc2, HC, HC, HC, HC);
  cast_launch(Wl3, Wc3, Cc, HC, HC, 0);
  cast_launch(Wr3, Wc3, Cc, HC, HC, Cc);
  cast_launch(x, hb, N, IN, Kp1, 0);  // x -> bf16 padded to 96, staged in hb

  // ---- CSR build (by dst) ----
  hipMemsetAsync(deg, 0, (size_t)N * 4, stream);
  int tb = 256;
  k_hist<<<(ET + tb - 1) / tb, tb, 0, stream>>>(ei, E, N, deg);
  int nb = (N + 255) / 256;
  k_scan1<<<nb, 256, 0, stream>>>(deg, N, rp, bsum);
  k_scan2<<<1, 64, 0, stream>>>(bsum, nb);
  k_scan3<<<(N + 255) / 256, 256, 0, stream>>>(rp, bsum, N);
  k_copy_i32<<<(N + 255) / 256, 256, 0, stream>>>(rp, cursor, N);
  k_scatter<<<(ET + tb - 1) / tb, tb, 0, stream>>>(ei, E, N, cursor, srcs, dsts);

  const int LOG_BLOCKS = 2048;             // 8192 waves, grid-stride
  int nodeBlocks = (N + 3) / 4;            // 4 waves/block, wave per node
  int mb = (N + 127) / 128;

  // ---- layer 1 ----
  {
    dim3 g(2 * HC / 128, mb);
    gemm_mfma<<<g, 256, 0, stream>>>(hb, Wc1, bl1, br1, HC, xlr, N, Kp1, 2 * HC);
    k_logits<512, 4><<<LOG_BLOCKS, 256, 0, stream>>>(xlr, xlr + HC, 2 * HC, srcs, dsts, ET, att1, ls);
    k_stats_alpha<4><<<nodeBlocks, 256, 0, stream>>>(ls, rp, N);
    k_aggregate<512, 4, true, __hip_bfloat16><<<nodeBlocks, 256, 0, stream>>>(
        xlr, 2 * HC, ls, rp, srcs, b1, N, hb);
  }
  // ---- layer 2 ----
  {
    dim3 g(2 * HC / 128, mb);
    gemm_mfma<<<g, 256, 0, stream>>>(hb, Wc2, bl2, br2, HC, xlr, N, HC, 2 * HC);
    k_logits<512, 4><<<LOG_BLOCKS, 256, 0, stream>>>(xlr, xlr + HC, 2 * HC, srcs, dsts, ET, att2, ls);
    k_stats_alpha<4><<<nodeBlocks, 256, 0, stream>>>(ls, rp, N);
    k_aggregate<512, 4, true, __hip_bfloat16><<<nodeBlocks, 256, 0, stream>>>(
        xlr, 2 * HC, ls, rp, srcs, b2, N, hb);
  }
  // ---- layer 3 (1 head, 128 ch, fp32 out, no ELU) ----
  {
    dim3 g(2 * Cc / 128, mb);
    gemm_mfma<<<g, 256, 0, stream>>>(hb, Wc3, bl3, br3, Cc, xlr, N, HC, 2 * Cc);
    k_logits<128, 1><<<LOG_BLOCKS, 256, 0, stream>>>(xlr, xlr + Cc, 2 * Cc, srcs, dsts, ET, att3, ls);
    k_stats_alpha<1><<<nodeBlocks, 256, 0, stream>>>(ls, rp, N);
    k_aggregate<128, 1, false, float><<<nodeBlocks, 256, 0, stream>>>(
        xlr, 2 * Cc, ls, rp, srcs, b3, N, out);
  }
}

// Round 4
// 242.973 us; speedup vs baseline: 4.3513x; 1.2662x over previous
//
#include <hip/hip_runtime.h>
#include <hip/hip_bf16.h>
#include <math.h>

typedef __attribute__((ext_vector_type(8))) short short8;
typedef __attribute__((ext_vector_type(4))) float f32x4;
typedef __attribute__((ext_vector_type(2))) float f32x2;

__device__ __forceinline__ float bf2f(unsigned short u) {
  union { unsigned int i; float f; } x; x.i = ((unsigned int)u) << 16; return x.f;
}

__device__ __forceinline__ void load_lds16(const void* g, void* l) {
  __builtin_amdgcn_global_load_lds(
      (const __attribute__((address_space(1))) unsigned int*)g,
      (__attribute__((address_space(3))) unsigned int*)l, 16, 0, 0);
}

// ---------------- bf16 MFMA GEMM, bf16 output ----------------
__global__ __launch_bounds__(256) void gemm_mfma(
    const __hip_bfloat16* __restrict__ A, const __hip_bfloat16* __restrict__ B,
    const float* __restrict__ bl, const float* __restrict__ br, int halfN,
    __hip_bfloat16* __restrict__ out, int M, int K, int Nout) {
  __shared__ __hip_bfloat16 As[128 * 32];
  __shared__ __hip_bfloat16 Bs[128 * 32];
  int t = threadIdx.x;
  int w = t >> 6, l = t & 63;
  int lr = l & 15, lh = l >> 4;
  int wr = w >> 1, wc = w & 1;
  int m0 = blockIdx.y * 128, n0 = blockIdx.x * 128;
  f32x4 acc[4][4] = {};
  int nk = K >> 5;
  for (int ks = 0; ks < nk; ++ks) {
    int k0 = ks << 5;
#pragma unroll
    for (int p = 0; p < 2; ++p) {
      int c = p * 256 + t;
      int row = c >> 2, sub = c & 3;
      int gm = m0 + row; if (gm >= M) gm = M - 1;
      const __hip_bfloat16* gsrc = A + (size_t)gm * K + k0 + sub * 8;
      char* ldst = (char*)As + (size_t)(p * 256 + w * 64) * 16;
      load_lds16(gsrc, ldst);
    }
#pragma unroll
    for (int p = 0; p < 2; ++p) {
      int c = p * 256 + t;
      int row = c >> 2, sub = c & 3;
      const __hip_bfloat16* gsrc = B + (size_t)(n0 + row) * K + k0 + sub * 8;
      char* ldst = (char*)Bs + (size_t)(p * 256 + w * 64) * 16;
      load_lds16(gsrc, ldst);
    }
    __syncthreads();
    short8 af[4], bf[4];
#pragma unroll
    for (int mt = 0; mt < 4; ++mt)
      af[mt] = *(const short8*)(As + (size_t)(wr * 64 + mt * 16 + lr) * 32 + lh * 8);
#pragma unroll
    for (int nt = 0; nt < 4; ++nt)
      bf[nt] = *(const short8*)(Bs + (size_t)(wc * 64 + nt * 16 + lr) * 32 + lh * 8);
#pragma unroll
    for (int mt = 0; mt < 4; ++mt)
#pragma unroll
      for (int nt = 0; nt < 4; ++nt)
        acc[mt][nt] = __builtin_amdgcn_mfma_f32_16x16x32_bf16(af[mt], bf[nt], acc[mt][nt], 0, 0, 0);
    __syncthreads();
  }
#pragma unroll
  for (int mt = 0; mt < 4; ++mt) {
#pragma unroll
    for (int r = 0; r < 4; ++r) {
      int gm = m0 + wr * 64 + mt * 16 + lh * 4 + r;
      if (gm >= M) continue;
#pragma unroll
      for (int nt = 0; nt < 4; ++nt) {
        int gn = n0 + wc * 64 + nt * 16 + lr;
        float bv = (gn < halfN) ? bl[gn] : br[gn - halfN];
        out[(size_t)gm * Nout + gn] = __float2bfloat16(acc[mt][nt][r] + bv);
      }
    }
  }
}

// ---------------- fused cast (all weights + x) ----------------
struct CastSeg { const float* src; __hip_bfloat16* dst; int rows, K, Kp, row0, start; };
struct CastArgs { CastSeg s[7]; int total; };

__global__ __launch_bounds__(256) void k_cast_all(CastArgs A) {
  int stride = gridDim.x * blockDim.x;
  for (int i = blockIdx.x * blockDim.x + threadIdx.x; i < A.total; i += stride) {
    int si = 0;
#pragma unroll
    for (int j = 1; j < 7; j++) if (i >= A.s[j].start) si = j;
    CastSeg sg = A.s[si];
    int li = i - sg.start;
    int r = li / sg.Kp, k = li - r * sg.Kp;
    float v = (k < sg.K) ? sg.src[(size_t)r * sg.K + k] : 0.f;
    sg.dst[(size_t)(sg.row0 + r) * sg.Kp + k] = __float2bfloat16(v);
  }
}

// ---------------- CSR construction ----------------
__global__ void k_hist(const int* __restrict__ ei, int E, int N, int* __restrict__ deg) {
  int e = blockIdx.x * blockDim.x + threadIdx.x;
  int ET = E + N;
  if (e >= ET) return;
  int d = (e < E) ? ei[E + e] : (e - E);
  atomicAdd(&deg[d], 1);
}

__global__ __launch_bounds__(256) void k_scan_one(const int* __restrict__ deg, int N,
                                                  int* __restrict__ rp, int* __restrict__ cursor) {
  __shared__ int part[256];
  int t = threadIdx.x;
  int chunk = (N + 255) / 256;
  int lo = t * chunk;
  int hi = lo + chunk; if (hi > N) hi = N;
  int s = 0;
  for (int i = lo; i < hi; ++i) s += deg[i];
  part[t] = s;
  __syncthreads();
  for (int off = 1; off < 256; off <<= 1) {
    int x = (t >= off) ? part[t - off] : 0;
    __syncthreads();
    part[t] += x;
    __syncthreads();
  }
  int run = (t == 0) ? 0 : part[t - 1];
  for (int i = lo; i < hi; ++i) {
    rp[i] = run;
    cursor[i] = run;
    run += deg[i];
  }
  if (t == 255) rp[N] = run;
}

__global__ void k_scatter(const int* __restrict__ ei, int E, int N,
                          int* __restrict__ cursor, int* __restrict__ srcs) {
  int e = blockIdx.x * blockDim.x + threadIdx.x;
  int ET = E + N;
  if (e >= ET) return;
  int s = (e < E) ? ei[e] : (e - E);
  int d = (e < E) ? ei[E + e] : (e - E);
  int pos = atomicAdd(&cursor[d], 1);
  srcs[pos] = s;
}

// ---------------- fused edge phase: logits + online softmax + aggregate ----------------
// One wave per node. Lane layout (Hn=4,HC=512): head = lane>>4, 8 ch/lane.
// Online-softmax: running max m, denom sum, rescaled acc. Single gather of xl[src]/edge.
template <int HC, int Hn, bool ELU, typename OutT>
__global__ __launch_bounds__(256) void k_edge_fused(
    const __hip_bfloat16* __restrict__ xl, const __hip_bfloat16* __restrict__ xr, int LD,
    const int* __restrict__ rp, const int* __restrict__ srcs,
    const float* __restrict__ att, const float* __restrict__ bias,
    int N, OutT* __restrict__ out) {
  const int CPL = HC / 64;
  int lane = threadIdx.x & 63;
  int n = (blockIdx.x * blockDim.x + threadIdx.x) >> 6;
  if (n >= N) return;
  float a[CPL], xrv[CPL];
#pragma unroll
  for (int c = 0; c < CPL; c++) a[c] = att[lane * CPL + c];
  if constexpr (CPL == 8) {
    short8 v = *(const short8*)(xr + (size_t)n * LD + lane * 8);
#pragma unroll
    for (int c = 0; c < 8; c++) xrv[c] = bf2f((unsigned short)v[c]);
  } else {
    unsigned int v = *(const unsigned int*)(xr + (size_t)n * LD + lane * 2);
    xrv[0] = bf2f((unsigned short)(v & 0xffff));
    xrv[1] = bf2f((unsigned short)(v >> 16));
  }
  int s0 = rp[n], s1 = rp[n + 1];
  float m = -INFINITY, sum = 0.f;
  float acc[CPL] = {};
  // software pipeline: row for iteration i is loaded during iteration i-1
  int s_nxt = srcs[s0];
  short8 v8; unsigned int v4;
  if constexpr (CPL == 8) v8 = *(const short8*)(xl + (size_t)s_nxt * LD + lane * 8);
  else v4 = *(const unsigned int*)(xl + (size_t)s_nxt * LD + lane * 2);
  for (int i = s0; i < s1; ++i) {
    float xv[CPL];
    if constexpr (CPL == 8) {
#pragma unroll
      for (int c = 0; c < 8; c++) xv[c] = bf2f((unsigned short)v8[c]);
    } else {
      xv[0] = bf2f((unsigned short)(v4 & 0xffff));
      xv[1] = bf2f((unsigned short)(v4 >> 16));
    }
    if (i + 1 < s1) {
      s_nxt = srcs[i + 1];
      if constexpr (CPL == 8) v8 = *(const short8*)(xl + (size_t)s_nxt * LD + lane * 8);
      else v4 = *(const unsigned int*)(xl + (size_t)s_nxt * LD + lane * 2);
    }
    float p = 0.f;
#pragma unroll
    for (int c = 0; c < CPL; c++) {
      float v = xv[c] + xrv[c];
      v = v > 0.f ? v : 0.2f * v;
      p += v * a[c];
    }
    // reduce logit across the head's lanes
    const int RO = (Hn == 4) ? 8 : 32;
#pragma unroll
    for (int off = 1; off <= RO; off <<= 1) p += __shfl_xor(p, off, 64);
    // online softmax update
    float mn = fmaxf(m, p);
    float corr = __expf(m - mn);
    float wgt = __expf(p - mn);
    sum = sum * corr + wgt;
#pragma unroll
    for (int c = 0; c < CPL; c++) acc[c] = acc[c] * corr + wgt * xv[c];
    m = mn;
  }
  float inv = 1.f / (sum + 1e-16f);
#pragma unroll
  for (int c = 0; c < CPL; c++) {
    float r = acc[c] * inv + bias[lane * CPL + c];
    if (ELU) r = r > 0.f ? r : expm1f(r);
    acc[c] = r;
  }
  if constexpr (sizeof(OutT) == 2) {
    short8 o;
#pragma unroll
    for (int c = 0; c < CPL; c++) {
      __hip_bfloat16 bv = __float2bfloat16(acc[c]);
      o[c] = __builtin_bit_cast(short, bv);
    }
    *(short8*)((__hip_bfloat16*)out + (size_t)n * HC + lane * CPL) = o;
  } else {
    f32x2 o; o.x = acc[0]; o.y = acc[1];
    *(f32x2*)((float*)out + (size_t)n * HC + lane * 2) = o;
  }
}

extern "C" void kernel_launch(void* const* d_in, const int* in_sizes, int n_in,
                              void* d_out, int out_size, void* d_ws, size_t ws_size,
                              hipStream_t stream) {
  const int IN = 77, Kp1 = 96, Hh = 4, Cc = 128, HC = Hh * Cc;  // 512
  const int N = in_sizes[0] / IN;
  const int E = in_sizes[1] / 2;
  const int ET = E + N;

  const float* x   = (const float*)d_in[0];
  const int*   ei  = (const int*)d_in[1];
  const float* Wl1 = (const float*)d_in[2];  const float* bl1 = (const float*)d_in[3];
  const float* Wr1 = (const float*)d_in[4];  const float* br1 = (const float*)d_in[5];
  const float* att1= (const float*)d_in[6];  const float* b1  = (const float*)d_in[7];
  const float* Wl2 = (const float*)d_in[8];  const float* bl2 = (const float*)d_in[9];
  const float* Wr2 = (const float*)d_in[10]; const float* br2 = (const float*)d_in[11];
  const float* att2= (const float*)d_in[12]; const float* b2  = (const float*)d_in[13];
  const float* Wl3 = (const float*)d_in[14]; const float* bl3 = (const float*)d_in[15];
  const float* Wr3 = (const float*)d_in[16]; const float* br3 = (const float*)d_in[17];
  const float* att3= (const float*)d_in[18]; const float* b3  = (const float*)d_in[19];
  float* out = (float*)d_out;

  char* w = (char*)d_ws;
  size_t off = 0;
  auto alloc = [&](size_t bytes) -> void* {
    void* p = w + off;
    off += (bytes + 255) & ~(size_t)255;
    return p;
  };
  __hip_bfloat16* xlr = (__hip_bfloat16*)alloc((size_t)N * 2 * HC * 2);
  __hip_bfloat16* hb  = (__hip_bfloat16*)alloc((size_t)N * HC * 2);
  __hip_bfloat16* Wc1 = (__hip_bfloat16*)alloc((size_t)2 * HC * Kp1 * 2);
  __hip_bfloat16* Wc2 = (__hip_bfloat16*)alloc((size_t)2 * HC * HC * 2);
  __hip_bfloat16* Wc3 = (__hip_bfloat16*)alloc((size_t)2 * Cc * HC * 2);
  int*   deg    = (int*)alloc((size_t)N * 4);
  int*   rp     = (int*)alloc((size_t)(N + 1) * 4);
  int*   cursor = (int*)alloc((size_t)N * 4);
  int*   srcs   = (int*)alloc((size_t)ET * 4);

  // ---- fused casts ----
  CastArgs CA;
  int cum = 0;
  auto seg = [&](int idx, const float* src, __hip_bfloat16* dst, int rows, int K, int Kp, int row0) {
    CA.s[idx] = {src, dst, rows, K, Kp, row0, cum};
    cum += rows * Kp;
  };
  seg(0, Wl1, Wc1, HC, IN, Kp1, 0);
  seg(1, Wr1, Wc1, HC, IN, Kp1, HC);
  seg(2, Wl2, Wc2, HC, HC, HC, 0);
  seg(3, Wr2, Wc2, HC, HC, HC, HC);
  seg(4, Wl3, Wc3, Cc, HC, HC, 0);
  seg(5, Wr3, Wc3, Cc, HC, HC, Cc);
  seg(6, x,   hb,  N,  IN, Kp1, 0);
  CA.total = cum;
  k_cast_all<<<1024, 256, 0, stream>>>(CA);

  // ---- CSR build (by dst) ----
  hipMemsetAsync(deg, 0, (size_t)N * 4, stream);
  int tb = 256;
  k_hist<<<(ET + tb - 1) / tb, tb, 0, stream>>>(ei, E, N, deg);
  k_scan_one<<<1, 256, 0, stream>>>(deg, N, rp, cursor);
  k_scatter<<<(ET + tb - 1) / tb, tb, 0, stream>>>(ei, E, N, cursor, srcs);

  int nodeBlocks = (N + 3) / 4;  // 4 waves/block, one wave per node
  int mb = (N + 127) / 128;

  // ---- layer 1 ----
  {
    dim3 g(2 * HC / 128, mb);
    gemm_mfma<<<g, 256, 0, stream>>>(hb, Wc1, bl1, br1, HC, xlr, N, Kp1, 2 * HC);
    k_edge_fused<512, 4, true, __hip_bfloat16><<<nodeBlocks, 256, 0, stream>>>(
        xlr, xlr + HC, 2 * HC, rp, srcs, att1, b1, N, hb);
  }
  // ---- layer 2 ----
  {
    dim3 g(2 * HC / 128, mb);
    gemm_mfma<<<g, 256, 0, stream>>>(hb, Wc2, bl2, br2, HC, xlr, N, HC, 2 * HC);
    k_edge_fused<512, 4, true, __hip_bfloat16><<<nodeBlocks, 256, 0, stream>>>(
        xlr, xlr + HC, 2 * HC, rp, srcs, att2, b2, N, hb);
  }
  // ---- layer 3 (1 head, 128 ch, fp32 out, no ELU) ----
  {
    dim3 g(2 * Cc / 128, mb);
    gemm_mfma<<<g, 256, 0, stream>>>(hb, Wc3, bl3, br3, Cc, xlr, N, HC, 2 * Cc);
    k_edge_fused<128, 1, false, float><<<nodeBlocks, 256, 0, stream>>>(
        xlr, xlr + Cc, 2 * Cc, rp, srcs, att3, b3, N, out);
  }
}

// Round 5
// 225.002 us; speedup vs baseline: 4.6989x; 1.0799x over previous
//
#include <hip/hip_runtime.h>
#include <hip/hip_bf16.h>
#include <math.h>

typedef __attribute__((ext_vector_type(8))) short short8;
typedef __attribute__((ext_vector_type(4))) float f32x4;
typedef __attribute__((ext_vector_type(2))) float f32x2;

__device__ __forceinline__ float bf2f(unsigned short u) {
  union { unsigned int i; float f; } x; x.i = ((unsigned int)u) << 16; return x.f;
}

__device__ __forceinline__ void load_lds16(const void* g, void* l) {
  __builtin_amdgcn_global_load_lds(
      (const __attribute__((address_space(1))) unsigned int*)g,
      (__attribute__((address_space(3))) unsigned int*)l, 16, 0, 0);
}

// ---------------- bf16 MFMA GEMM, bf16 output ----------------
__global__ __launch_bounds__(256) void gemm_mfma(
    const __hip_bfloat16* __restrict__ A, const __hip_bfloat16* __restrict__ B,
    const float* __restrict__ bl, const float* __restrict__ br, int halfN,
    __hip_bfloat16* __restrict__ out, int M, int K, int Nout) {
  __shared__ __hip_bfloat16 As[128 * 32];
  __shared__ __hip_bfloat16 Bs[128 * 32];
  int t = threadIdx.x;
  int w = t >> 6, l = t & 63;
  int lr = l & 15, lh = l >> 4;
  int wr = w >> 1, wc = w & 1;
  int m0 = blockIdx.y * 128, n0 = blockIdx.x * 128;
  f32x4 acc[4][4] = {};
  int nk = K >> 5;
  for (int ks = 0; ks < nk; ++ks) {
    int k0 = ks << 5;
#pragma unroll
    for (int p = 0; p < 2; ++p) {
      int c = p * 256 + t;
      int row = c >> 2, sub = c & 3;
      int gm = m0 + row; if (gm >= M) gm = M - 1;
      const __hip_bfloat16* gsrc = A + (size_t)gm * K + k0 + sub * 8;
      char* ldst = (char*)As + (size_t)(p * 256 + w * 64) * 16;
      load_lds16(gsrc, ldst);
    }
#pragma unroll
    for (int p = 0; p < 2; ++p) {
      int c = p * 256 + t;
      int row = c >> 2, sub = c & 3;
      const __hip_bfloat16* gsrc = B + (size_t)(n0 + row) * K + k0 + sub * 8;
      char* ldst = (char*)Bs + (size_t)(p * 256 + w * 64) * 16;
      load_lds16(gsrc, ldst);
    }
    __syncthreads();
    short8 af[4], bf[4];
#pragma unroll
    for (int mt = 0; mt < 4; ++mt)
      af[mt] = *(const short8*)(As + (size_t)(wr * 64 + mt * 16 + lr) * 32 + lh * 8);
#pragma unroll
    for (int nt = 0; nt < 4; ++nt)
      bf[nt] = *(const short8*)(Bs + (size_t)(wc * 64 + nt * 16 + lr) * 32 + lh * 8);
#pragma unroll
    for (int mt = 0; mt < 4; ++mt)
#pragma unroll
      for (int nt = 0; nt < 4; ++nt)
        acc[mt][nt] = __builtin_amdgcn_mfma_f32_16x16x32_bf16(af[mt], bf[nt], acc[mt][nt], 0, 0, 0);
    __syncthreads();
  }
#pragma unroll
  for (int mt = 0; mt < 4; ++mt) {
#pragma unroll
    for (int r = 0; r < 4; ++r) {
      int gm = m0 + wr * 64 + mt * 16 + lh * 4 + r;
      if (gm >= M) continue;
#pragma unroll
      for (int nt = 0; nt < 4; ++nt) {
        int gn = n0 + wc * 64 + nt * 16 + lr;
        float bv = (gn < halfN) ? bl[gn] : br[gn - halfN];
        out[(size_t)gm * Nout + gn] = __float2bfloat16(acc[mt][nt][r] + bv);
      }
    }
  }
}

// ---------------- fused cast (all weights + x) ----------------
struct CastSeg { const float* src; __hip_bfloat16* dst; int rows, K, Kp, row0, start; };
struct CastArgs { CastSeg s[7]; int total; };

__global__ __launch_bounds__(256) void k_cast_all(CastArgs A) {
  int stride = gridDim.x * blockDim.x;
  for (int i = blockIdx.x * blockDim.x + threadIdx.x; i < A.total; i += stride) {
    int si = 0;
#pragma unroll
    for (int j = 1; j < 7; j++) if (i >= A.s[j].start) si = j;
    CastSeg sg = A.s[si];
    int li = i - sg.start;
    int r = li / sg.Kp, k = li - r * sg.Kp;
    float v = (k < sg.K) ? sg.src[(size_t)r * sg.K + k] : 0.f;
    sg.dst[(size_t)(sg.row0 + r) * sg.Kp + k] = __float2bfloat16(v);
  }
}

// ---------------- CSR construction ----------------
__global__ void k_hist(const int* __restrict__ ei, int E, int N, int* __restrict__ deg) {
  int e = blockIdx.x * blockDim.x + threadIdx.x;
  int ET = E + N;
  if (e >= ET) return;
  int d = (e < E) ? ei[E + e] : (e - E);
  atomicAdd(&deg[d], 1);
}

__global__ __launch_bounds__(256) void k_scan_one(const int* __restrict__ deg, int N,
                                                  int* __restrict__ rp, int* __restrict__ cursor) {
  __shared__ int part[256];
  int t = threadIdx.x;
  int chunk = (N + 255) / 256;
  int lo = t * chunk;
  int hi = lo + chunk; if (hi > N) hi = N;
  int s = 0;
  for (int i = lo; i < hi; ++i) s += deg[i];
  part[t] = s;
  __syncthreads();
  for (int off = 1; off < 256; off <<= 1) {
    int x = (t >= off) ? part[t - off] : 0;
    __syncthreads();
    part[t] += x;
    __syncthreads();
  }
  int run = (t == 0) ? 0 : part[t - 1];
  for (int i = lo; i < hi; ++i) {
    rp[i] = run;
    cursor[i] = run;
    run += deg[i];
  }
  if (t == 255) rp[N] = run;
}

__global__ void k_scatter(const int* __restrict__ ei, int E, int N,
                          int* __restrict__ cursor, int* __restrict__ srcs) {
  int e = blockIdx.x * blockDim.x + threadIdx.x;
  int ET = E + N;
  if (e >= ET) return;
  int s = (e < E) ? ei[e] : (e - E);
  int d = (e < E) ? ei[E + e] : (e - E);
  int pos = atomicAdd(&cursor[d], 1);
  srcs[pos] = s;
}

// ---------------- fused edge phase: logits + defer-max softmax + aggregate ----------------
template <int CPL> struct VecSel;
template <> struct VecSel<8> { using T = short8; };
template <> struct VecSel<2> { using T = unsigned int; };

// One wave per node. Defer-max (T13): m only updates when some head's logit exceeds
// m+8; fast path is pure FMA accumulation (no serial rescale chain). 2-deep
// prefetch + paired processing for memory-latency overlap.
template <int HC, int Hn, bool ELU, typename OutT>
__global__ __launch_bounds__(256) void k_edge_fused(
    const __hip_bfloat16* __restrict__ xl, const __hip_bfloat16* __restrict__ xr, int LD,
    const int* __restrict__ rp, const int* __restrict__ srcs,
    const float* __restrict__ att, const float* __restrict__ bias,
    int N, OutT* __restrict__ out) {
  const int CPL = HC / 64;
  using VecT = typename VecSel<CPL>::T;
  int lane = threadIdx.x & 63;
  int n = (blockIdx.x * blockDim.x + threadIdx.x) >> 6;
  if (n >= N) return;
  float a[CPL], xrv[CPL];
#pragma unroll
  for (int c = 0; c < CPL; c++) a[c] = att[lane * CPL + c];
  if constexpr (CPL == 8) {
    short8 v = *(const short8*)(xr + (size_t)n * LD + lane * 8);
#pragma unroll
    for (int c = 0; c < 8; c++) xrv[c] = bf2f((unsigned short)v[c]);
  } else {
    unsigned int v = *(const unsigned int*)(xr + (size_t)n * LD + lane * 2);
    xrv[0] = bf2f((unsigned short)(v & 0xffff));
    xrv[1] = bf2f((unsigned short)(v >> 16));
  }
  int s0 = rp[n], s1 = rp[n + 1];
  float m = -INFINITY, sum = 0.f;
  float acc[CPL] = {};

  auto loadrow = [&](int s) -> VecT {
    return *(const VecT*)(xl + (size_t)s * LD + lane * CPL);
  };
  auto proc = [&](VecT v) {
    float xv[CPL];
    if constexpr (CPL == 8) {
#pragma unroll
      for (int c = 0; c < 8; c++) xv[c] = bf2f((unsigned short)v[c]);
    } else {
      xv[0] = bf2f((unsigned short)(v & 0xffff));
      xv[1] = bf2f((unsigned short)(v >> 16));
    }
    float p = 0.f;
#pragma unroll
    for (int c = 0; c < CPL; c++) {
      float t2 = xv[c] + xrv[c];
      t2 = t2 > 0.f ? t2 : 0.2f * t2;
      p = fmaf(t2, a[c], p);
    }
    const int RO = (Hn == 4) ? 8 : 32;
#pragma unroll
    for (int off = 1; off <= RO; off <<= 1) p += __shfl_xor(p, off, 64);
    if (__any(p > m + 8.f)) {  // rare: rescale to new reference max
      float mn = fmaxf(m, p);
      float corr = __expf(m - mn);
      float wgt = __expf(p - mn);
      sum = sum * corr + wgt;
#pragma unroll
      for (int c = 0; c < CPL; c++) acc[c] = fmaf(acc[c], corr, wgt * xv[c]);
      m = mn;
    } else {  // fast path: independent FMA accumulation
      float wgt = __expf(p - m);
      sum += wgt;
#pragma unroll
      for (int c = 0; c < CPL; c++) acc[c] = fmaf(wgt, xv[c], acc[c]);
    }
  };

  VecT b0, b1;
  b0 = loadrow(srcs[s0]);
  if (s0 + 1 < s1) b1 = loadrow(srcs[s0 + 1]);
  int i = s0;
  for (; i + 1 < s1; i += 2) {
    VecT n0v, n1v;
    bool pf = (i + 2 < s1);
    if (pf) {
      int j0 = srcs[i + 2];
      int j1 = (i + 3 < s1) ? srcs[i + 3] : j0;
      n0v = loadrow(j0);
      n1v = loadrow(j1);
    }
    proc(b0);
    proc(b1);
    if (pf) { b0 = n0v; b1 = n1v; }
  }
  if (i < s1) proc(b0);

  float inv = 1.f / (sum + 1e-16f);
#pragma unroll
  for (int c = 0; c < CPL; c++) {
    float r = acc[c] * inv + bias[lane * CPL + c];
    if (ELU) r = r > 0.f ? r : expm1f(r);
    acc[c] = r;
  }
  if constexpr (sizeof(OutT) == 2) {
    short8 o;
#pragma unroll
    for (int c = 0; c < CPL; c++) {
      __hip_bfloat16 bv = __float2bfloat16(acc[c]);
      o[c] = __builtin_bit_cast(short, bv);
    }
    *(short8*)((__hip_bfloat16*)out + (size_t)n * HC + lane * CPL) = o;
  } else {
    f32x2 o; o.x = acc[0]; o.y = acc[1];
    *(f32x2*)((float*)out + (size_t)n * HC + lane * 2) = o;
  }
}

extern "C" void kernel_launch(void* const* d_in, const int* in_sizes, int n_in,
                              void* d_out, int out_size, void* d_ws, size_t ws_size,
                              hipStream_t stream) {
  const int IN = 77, Kp1 = 96, Hh = 4, Cc = 128, HC = Hh * Cc;  // 512
  const int N = in_sizes[0] / IN;
  const int E = in_sizes[1] / 2;
  const int ET = E + N;

  const float* x   = (const float*)d_in[0];
  const int*   ei  = (const int*)d_in[1];
  const float* Wl1 = (const float*)d_in[2];  const float* bl1 = (const float*)d_in[3];
  const float* Wr1 = (const float*)d_in[4];  const float* br1 = (const float*)d_in[5];
  const float* att1= (const float*)d_in[6];  const float* b1  = (const float*)d_in[7];
  const float* Wl2 = (const float*)d_in[8];  const float* bl2 = (const float*)d_in[9];
  const float* Wr2 = (const float*)d_in[10]; const float* br2 = (const float*)d_in[11];
  const float* att2= (const float*)d_in[12]; const float* b2  = (const float*)d_in[13];
  const float* Wl3 = (const float*)d_in[14]; const float* bl3 = (const float*)d_in[15];
  const float* Wr3 = (const float*)d_in[16]; const float* br3 = (const float*)d_in[17];
  const float* att3= (const float*)d_in[18]; const float* b3  = (const float*)d_in[19];
  float* out = (float*)d_out;

  char* w = (char*)d_ws;
  size_t off = 0;
  auto alloc = [&](size_t bytes) -> void* {
    void* p = w + off;
    off += (bytes + 255) & ~(size_t)255;
    return p;
  };
  __hip_bfloat16* xlr = (__hip_bfloat16*)alloc((size_t)N * 2 * HC * 2);
  __hip_bfloat16* hb  = (__hip_bfloat16*)alloc((size_t)N * HC * 2);
  __hip_bfloat16* Wc1 = (__hip_bfloat16*)alloc((size_t)2 * HC * Kp1 * 2);
  __hip_bfloat16* Wc2 = (__hip_bfloat16*)alloc((size_t)2 * HC * HC * 2);
  __hip_bfloat16* Wc3 = (__hip_bfloat16*)alloc((size_t)2 * Cc * HC * 2);
  int*   deg    = (int*)alloc((size_t)N * 4);
  int*   rp     = (int*)alloc((size_t)(N + 1) * 4);
  int*   cursor = (int*)alloc((size_t)N * 4);
  int*   srcs   = (int*)alloc((size_t)ET * 4);

  // ---- fused casts ----
  CastArgs CA;
  int cum = 0;
  auto seg = [&](int idx, const float* src, __hip_bfloat16* dst, int rows, int K, int Kp, int row0) {
    CA.s[idx] = {src, dst, rows, K, Kp, row0, cum};
    cum += rows * Kp;
  };
  seg(0, Wl1, Wc1, HC, IN, Kp1, 0);
  seg(1, Wr1, Wc1, HC, IN, Kp1, HC);
  seg(2, Wl2, Wc2, HC, HC, HC, 0);
  seg(3, Wr2, Wc2, HC, HC, HC, HC);
  seg(4, Wl3, Wc3, Cc, HC, HC, 0);
  seg(5, Wr3, Wc3, Cc, HC, HC, Cc);
  seg(6, x,   hb,  N,  IN, Kp1, 0);
  CA.total = cum;
  k_cast_all<<<1024, 256, 0, stream>>>(CA);

  // ---- CSR build (by dst) ----
  hipMemsetAsync(deg, 0, (size_t)N * 4, stream);
  int tb = 256;
  k_hist<<<(ET + tb - 1) / tb, tb, 0, stream>>>(ei, E, N, deg);
  k_scan_one<<<1, 256, 0, stream>>>(deg, N, rp, cursor);
  k_scatter<<<(ET + tb - 1) / tb, tb, 0, stream>>>(ei, E, N, cursor, srcs);

  int nodeBlocks = (N + 3) / 4;  // 4 waves/block, one wave per node
  int mb = (N + 127) / 128;

  // ---- layer 1 ----
  {
    dim3 g(2 * HC / 128, mb);
    gemm_mfma<<<g, 256, 0, stream>>>(hb, Wc1, bl1, br1, HC, xlr, N, Kp1, 2 * HC);
    k_edge_fused<512, 4, true, __hip_bfloat16><<<nodeBlocks, 256, 0, stream>>>(
        xlr, xlr + HC, 2 * HC, rp, srcs, att1, b1, N, hb);
  }
  // ---- layer 2 ----
  {
    dim3 g(2 * HC / 128, mb);
    gemm_mfma<<<g, 256, 0, stream>>>(hb, Wc2, bl2, br2, HC, xlr, N, HC, 2 * HC);
    k_edge_fused<512, 4, true, __hip_bfloat16><<<nodeBlocks, 256, 0, stream>>>(
        xlr, xlr + HC, 2 * HC, rp, srcs, att2, b2, N, hb);
  }
  // ---- layer 3 (1 head, 128 ch, fp32 out, no ELU) ----
  {
    dim3 g(2 * Cc / 128, mb);
    gemm_mfma<<<g, 256, 0, stream>>>(hb, Wc3, bl3, br3, Cc, xlr, N, HC, 2 * Cc);
    k_edge_fused<128, 1, false, float><<<nodeBlocks, 256, 0, stream>>>(
        xlr, xlr + Cc, 2 * Cc, rp, srcs, att3, b3, N, out);
  }
}